// Round 6
// baseline (331.778 us; speedup 1.0000x reference)
//
#include <hip/hip_runtime.h>
#include <hip/hip_bf16.h>

#define CIN   256
#define COUT  32
#define IMG_H 96
#define IMG_W 96
#define HW    (IMG_H*IMG_W)
#define NB    2
#define NV    4
#define VSZ   64
#define NVOX  (VSZ*VSZ*VSZ)

// Kernel 1: 1x1 conv -> channel-last bf16 [b,v,h,w,c].
// One wave per block (64 px); each thread owns 1 px and ALL 32 couts, so
// every feature byte is loaded exactly once (R5 had 4x redundant loads).
// Weights/bias are wave-uniform -> scalar path (s_load_dwordx8/16), zero LDS.
// c-loop batched 16-deep: 512 FMA-cycles per batch hide ~900cyc HBM latency.
__global__ __launch_bounds__(64) void conv1x1_kernel(
    const float* __restrict__ features,   // [B,V,CIN,H,W] fp32
    const float* __restrict__ Wp,         // [COUT,CIN]
    const float* __restrict__ bp,         // [COUT]
    __hip_bfloat16* __restrict__ out)     // [B,V,H,W,COUT] bf16
{
    const int lane = threadIdx.x;
    const int bv   = blockIdx.y;
    const int px   = blockIdx.x*64 + lane;
    const float* f = features + (size_t)bv*CIN*HW + px;

    float acc[COUT];
    #pragma unroll
    for (int j = 0; j < COUT; ++j) acc[j] = bp[j];       // uniform -> s_load

    for (int cc = 0; cc < CIN; cc += 16) {
        float x[16];
        #pragma unroll
        for (int i = 0; i < 16; ++i)                     // 16 indep coalesced loads
            x[i] = f[(size_t)(cc + i)*HW];
        #pragma unroll
        for (int i = 0; i < 16; ++i) {
            #pragma unroll
            for (int j = 0; j < COUT; ++j)               // v_fmac v, s, v
                acc[j] += x[i] * Wp[(size_t)j*CIN + cc + i];
        }
    }

    union { uint4 u4[4]; __hip_bfloat16 h[COUT]; } pk;
    #pragma unroll
    for (int j = 0; j < COUT; ++j) pk.h[j] = __float2bfloat16(acc[j]);
    uint4* op = (uint4*)(out + ((size_t)(bv*HW + px))*COUT);
    #pragma unroll
    for (int k = 0; k < 4; ++k) op[k] = pk.u4[k];
}

// Kernel 2: two-phase. Phase 1: 256 threads = 64 voxels x 4 views, each
// thread computes ONE (voxel,view) projection (byte offsets + corner weights)
// into LDS -- removes the 4x duplicated projection math of R5 (~40% of VALU).
// Phase 2: 4 lanes/voxel, lane owns 8 channels; branchless gathers + streaming
// view-softmax (all-zero weights -> exp(0)=1 falls out automatically).
__global__ __launch_bounds__(256) void volgen_kernel(
    const __hip_bfloat16* __restrict__ feats,  // [B,V,H,W,COUT] bf16
    const float* __restrict__ proj,            // [B,V,3,4]
    const float* __restrict__ coords,          // [B,NVOX,3]
    float* __restrict__ out)                   // [B,COUT,NVOX]
{
    __shared__ int   OffL[NV][64][4];          // byte offsets, 4 KiB
    __shared__ float WgtL[NV][64][4];          // corner weights, 4 KiB
    __shared__ float T[COUT*65];               // output transpose, pad 65

    const int tid = threadIdx.x;
    const int b   = blockIdx.y;

    // ---- phase 1: one (voxel, view) pair per thread ----
    {
        const int vox  = tid >> 2;
        const int view = tid & 3;
        const int n    = blockIdx.x*64 + vox;
        const float* cp = coords + ((size_t)b*NVOX + n)*3;
        const float X = cp[0], Y = cp[1], Z = cp[2];
        const float* P = proj + (size_t)(b*NV + view)*12;   // 4-lane shared -> L1

        const float wz = P[8]*X + P[9]*Y + P[10]*Z + P[11];
        const bool  vz = wz > 0.f;
        const float rz = __builtin_amdgcn_rcpf(wz);
        float px = (P[0]*X + P[1]*Y + P[2]*Z + P[3]) * rz * (95.f/96.f);
        float py = (P[4]*X + P[5]*Y + P[6]*Z + P[7]) * rz * (95.f/96.f);
        px = vz ? px : 0.f;  py = vz ? py : 0.f;
        px = fminf(fmaxf(px, -1.0e6f), 1.0e6f);
        py = fminf(fmaxf(py, -1.0e6f), 1.0e6f);
        const float fx0 = floorf(px), fy0 = floorf(py);
        const int x0 = (int)fx0, y0 = (int)fy0, x1 = x0+1, y1 = y0+1;
        const float wx1 = px - fx0, wx0 = 1.f - wx1;
        const float wy1 = py - fy0, wy0 = 1.f - wy1;
        const bool vx0 = (unsigned)x0 < (unsigned)IMG_W;
        const bool vx1 = (unsigned)x1 < (unsigned)IMG_W;
        const bool vy0 = (unsigned)y0 < (unsigned)IMG_H;
        const bool vy1 = (unsigned)y1 < (unsigned)IMG_H;
        const int cx0 = min(max(x0, 0), IMG_W-1), cx1 = min(max(x1, 0), IMG_W-1);
        const int cy0 = min(max(y0, 0), IMG_H-1), cy1 = min(max(y1, 0), IMG_H-1);
        // byte offsets into feats (pixel record = COUT*2 = 64 B)
        const int base = (b*NV + view)*HW*(COUT*2);
        int4 of;
        of.x = base + (cy0*IMG_W + cx0)*(COUT*2);
        of.y = base + (cy0*IMG_W + cx1)*(COUT*2);
        of.z = base + (cy1*IMG_W + cx0)*(COUT*2);
        of.w = base + (cy1*IMG_W + cx1)*(COUT*2);
        float4 wg;
        wg.x = (vz & vx0 & vy0) ? wx0*wy0 : 0.f;
        wg.y = (vz & vx1 & vy0) ? wx1*wy0 : 0.f;
        wg.z = (vz & vx0 & vy1) ? wx0*wy1 : 0.f;
        wg.w = (vz & vx1 & vy1) ? wx1*wy1 : 0.f;
        *(int4*)  (&OffL[view][vox][0]) = of;
        *(float4*)(&WgtL[view][vox][0]) = wg;
    }
    __syncthreads();

    // ---- phase 2: gather + streaming softmax ----
    const int vl = tid >> 2;                   // voxel 0..63
    const int cg = tid & 3;                    // channel oct 0..3
    const char* fb = (const char*)feats + cg*16;

    float A[8], Bs[8];
    #pragma unroll
    for (int j = 0; j < 8; ++j) { A[j] = 0.f; Bs[j] = 0.f; }

    #pragma unroll
    for (int v = 0; v < NV; ++v) {
        const int4   of = *(const int4*)  (&OffL[v][vl][0]);   // b128, bcast over cg
        const float4 wg = *(const float4*)(&WgtL[v][vl][0]);
        const uint4 t0 = *(const uint4*)(fb + of.x);           // 4 loads in flight
        const uint4 t1 = *(const uint4*)(fb + of.y);
        const uint4 t2 = *(const uint4*)(fb + of.z);
        const uint4 t3 = *(const uint4*)(fb + of.w);

        float s[8];
        #pragma unroll
        for (int j = 0; j < 8; ++j) s[j] = 0.f;
        {
            const uint4* ts[4] = { &t0, &t1, &t2, &t3 };
            const float  ws[4] = { wg.x, wg.y, wg.z, wg.w };
            #pragma unroll
            for (int c = 0; c < 4; ++c) {
                const float w = ws[c];
                const unsigned tu[4] = { ts[c]->x, ts[c]->y, ts[c]->z, ts[c]->w };
                #pragma unroll
                for (int k = 0; k < 4; ++k) {
                    s[2*k]   += w * __uint_as_float(tu[k] << 16);
                    s[2*k+1] += w * __uint_as_float(tu[k] & 0xffff0000u);
                }
            }
        }
        #pragma unroll
        for (int j = 0; j < 8; ++j) {
            const float e = __expf(s[j]);      // all-zero weights -> e = 1
            A[j] += e;  Bs[j] += s[j]*e;
        }
    }

    #pragma unroll
    for (int j = 0; j < 8; ++j)
        T[(cg*8 + j)*65 + vl] = Bs[j] * __builtin_amdgcn_rcpf(A[j]);
    __syncthreads();

    const size_t ob = (size_t)b*COUT*NVOX + (size_t)blockIdx.x*64;
    #pragma unroll
    for (int i = 0; i < 8; ++i) {
        const int idx = i*256 + tid;
        const int ch = idx >> 6, vx = idx & 63;
        out[ob + (size_t)ch*NVOX + vx] = T[ch*65 + vx];
    }
}

extern "C" void kernel_launch(void* const* d_in, const int* in_sizes, int n_in,
                              void* d_out, int out_size, void* d_ws, size_t ws_size,
                              hipStream_t stream)
{
    const float* features = (const float*)d_in[0];   // [2,4,256,96,96]
    const float* proj     = (const float*)d_in[1];   // [2,4,3,4]
    const float* coords   = (const float*)d_in[2];   // [2,64,64,64,3]
    const float* Wp       = (const float*)d_in[3];   // [32,256]
    const float* bp       = (const float*)d_in[4];   // [32]
    float* out = (float*)d_out;                      // [2,32,64,64,64]
    __hip_bfloat16* featsT = (__hip_bfloat16*)d_ws;  // [2,4,96,96,32] bf16 = 4.72 MB

    hipLaunchKernelGGL(conv1x1_kernel, dim3(HW/64, NB*NV), dim3(64), 0, stream,
                       features, Wp, bp, featsT);
    hipLaunchKernelGGL(volgen_kernel, dim3(NVOX/64, NB), dim3(256), 0, stream,
                       featsT, proj, coords, out);
}